// Round 5
// baseline (144.050 us; speedup 1.0000x reference)
//
#include <hip/hip_runtime.h>

// FastAttention (Performer linear attention), B=4 H=8 N=4096 D=F=64, fp32.
// Two kernels, no prep, no atomics:
//   pass1 (1024 blocks): bfrag = bf16(proj*log2e) per block (L2-hot);
//          k' = exp2(k @ bfrag); block-private partial (ksum[64]||ctx[64]) -> ws
//   pass2 (1024 blocks): bfrag rebuild; Q fragment loads issued FIRST (overlap);
//          reduce head's 32 partials from ws (L2); q' = exp2(q @ bfrag);
//          denom = q'.(ksum+1e-6); out = q'*ctx*(1/denom)
// Column permutation: MFMA tile ft computes feature f = fp*4+ft (fp=lane&15),
// so V loads, stats and out stores are all dwordx4.
// ws: 1024 * 128 floats = 512 KB partials (every slot overwritten; poison-safe).

#define NHEADS 32
#define SEQ    4096
#define DDIM   64
#define LOG2E  1.44269504088896341f

typedef __attribute__((ext_vector_type(8))) short short8;
typedef __attribute__((ext_vector_type(4))) float floatx4;
typedef __attribute__((ext_vector_type(2))) float floatx2;

__device__ __forceinline__ short f2bf(float x) {
    unsigned int u = __float_as_uint(x);
    u += 0x7fffu + ((u >> 16) & 1u);
    return (short)(u >> 16);
}

__device__ __forceinline__ short8 load8_bf16(const float* __restrict__ p) {
    floatx4 a = *(const floatx4*)p;
    floatx4 b = *(const floatx4*)(p + 4);
    short8 t;
    t[0] = f2bf(a[0]); t[1] = f2bf(a[1]); t[2] = f2bf(a[2]); t[3] = f2bf(a[3]);
    t[4] = f2bf(b[0]); t[5] = f2bf(b[1]); t[6] = f2bf(b[2]); t[7] = f2bf(b[3]);
    return t;
}

__device__ __forceinline__ short8 load8_bf16_scale(const float* __restrict__ p, float s) {
    floatx4 a = *(const floatx4*)p;
    floatx4 b = *(const floatx4*)(p + 4);
    short8 t;
    t[0] = f2bf(a[0] * s); t[1] = f2bf(a[1] * s); t[2] = f2bf(a[2] * s); t[3] = f2bf(a[3] * s);
    t[4] = f2bf(b[0] * s); t[5] = f2bf(b[1] * s); t[6] = f2bf(b[2] * s); t[7] = f2bf(b[3] * s);
    return t;
}

__device__ __forceinline__ void make_bfrag(const float* __restrict__ proj,
                                           int fp, int g, short8 bfrag[4][2]) {
#pragma unroll
    for (int ft = 0; ft < 4; ++ft)
#pragma unroll
        for (int half = 0; half < 2; ++half)
            bfrag[ft][half] =
                load8_bf16_scale(proj + (fp * 4 + ft) * DDIM + half * 32 + g * 8, LOG2E);
}

__global__ __launch_bounds__(256, 4) void fa_pass1(const float* __restrict__ K,
                                                   const float* __restrict__ V,
                                                   const float* __restrict__ proj,
                                                   float* __restrict__ ws) {
    const int bid  = blockIdx.x;
    const int head = bid >> 5;          // 32 heads x 32 segments of 128 rows
    const int seg  = bid & 31;
    const int tid  = threadIdx.x;
    const int w    = tid >> 6;
    const int lane = tid & 63;
    const int fp   = lane & 15;
    const int g    = lane >> 4;
    const long hbase = (long)head * SEQ;

    short8 bfrag[4][2];
    make_bfrag(proj, fp, g, bfrag);

    float ksum[4] = {0.f, 0.f, 0.f, 0.f};
    float ctx[4]  = {0.f, 0.f, 0.f, 0.f};

#pragma unroll
    for (int it = 0; it < 2; ++it) {
        const int row0 = seg * 128 + it * 64 + w * 16;
        const float* ap = K + (hbase + row0 + fp) * DDIM;
        short8 a0 = load8_bf16(ap + g * 8);
        short8 a1 = load8_bf16(ap + 32 + g * 8);

        floatx4 acc[4];
#pragma unroll
        for (int ft = 0; ft < 4; ++ft) {
            floatx4 z = {0.f, 0.f, 0.f, 0.f};
            z = __builtin_amdgcn_mfma_f32_16x16x32_bf16(a0, bfrag[ft][0], z, 0, 0, 0);
            z = __builtin_amdgcn_mfma_f32_16x16x32_bf16(a1, bfrag[ft][1], z, 0, 0, 0);
            acc[ft] = z;
        }
        // C layout: col f = fp*4+ft, row = row0 + g*4 + r
#pragma unroll
        for (int r = 0; r < 4; ++r) {
            const floatx4 vv =
                *(const floatx4*)(V + (hbase + row0 + g * 4 + r) * DDIM + fp * 4);
#pragma unroll
            for (int ft = 0; ft < 4; ++ft) {
                float kp = __builtin_amdgcn_exp2f(acc[ft][r]);
                ksum[ft] += kp;
                ctx[ft]  += kp * vv[ft];
            }
        }
    }

#pragma unroll
    for (int ft = 0; ft < 4; ++ft) {
        ksum[ft] += __shfl_xor(ksum[ft], 16); ksum[ft] += __shfl_xor(ksum[ft], 32);
        ctx[ft]  += __shfl_xor(ctx[ft], 16);  ctx[ft]  += __shfl_xor(ctx[ft], 32);
    }
    __shared__ float smem[4][128];
    if (lane < 16) {
#pragma unroll
        for (int ft = 0; ft < 4; ++ft) {
            smem[w][fp * 4 + ft]      = ksum[ft];
            smem[w][64 + fp * 4 + ft] = ctx[ft];
        }
    }
    __syncthreads();
    if (tid < 128)
        ws[bid * 128 + tid] = smem[0][tid] + smem[1][tid] + smem[2][tid] + smem[3][tid];
}

__global__ __launch_bounds__(256, 4) void fa_pass2(const float* __restrict__ Q,
                                                   const float* __restrict__ proj,
                                                   const float* __restrict__ ws,
                                                   float* __restrict__ out) {
    const int bid  = blockIdx.x;
    const int head = bid >> 5;          // 32 heads x 32 segments of 128 rows
    const int seg  = bid & 31;
    const int tid  = threadIdx.x;
    const int w    = tid >> 6;
    const int lane = tid & 63;
    const int fp   = lane & 15;
    const int g    = lane >> 4;
    const long hbase = (long)head * SEQ;

    // Q fragment loads first: HBM stream overlaps the partial-reduce below.
    short8 qfrag[2][2];
#pragma unroll
    for (int it = 0; it < 2; ++it) {
        const float* qp_ = Q + (hbase + seg * 128 + it * 64 + w * 16 + fp) * DDIM;
        qfrag[it][0] = load8_bf16(qp_ + g * 8);
        qfrag[it][1] = load8_bf16(qp_ + 32 + g * 8);
    }

    short8 bfrag[4][2];
    make_bfrag(proj, fp, g, bfrag);

    // Reduce this head's 32 partials (wave w takes partials 8w..8w+7, L2-hot).
    floatx2 acc2 = {0.f, 0.f};
#pragma unroll
    for (int p = 0; p < 8; ++p) {
        floatx2 t = *(const floatx2*)(ws + (long)(head * 32 + w * 8 + p) * 128 + lane * 2);
        acc2[0] += t[0];
        acc2[1] += t[1];
    }
    __shared__ float smem[4][128];
    smem[w][lane * 2]     = acc2[0];
    smem[w][lane * 2 + 1] = acc2[1];
    __syncthreads();
    if (tid < 128)
        smem[0][tid] = smem[0][tid] + smem[1][tid] + smem[2][tid] + smem[3][tid];
    __syncthreads();
    floatx4 ksr  = *(const floatx4*)(&smem[0][fp * 4]);
    floatx4 ctxr = *(const floatx4*)(&smem[0][64 + fp * 4]);
#pragma unroll
    for (int ft = 0; ft < 4; ++ft) ksr[ft] += 1e-6f;

#pragma unroll
    for (int it = 0; it < 2; ++it) {
        const int row0 = seg * 128 + it * 64 + w * 16;
        float qp[4][4];
        float denom[4] = {0.f, 0.f, 0.f, 0.f};
#pragma unroll
        for (int ft = 0; ft < 4; ++ft) {
            floatx4 z = {0.f, 0.f, 0.f, 0.f};
            z = __builtin_amdgcn_mfma_f32_16x16x32_bf16(qfrag[it][0], bfrag[ft][0], z, 0, 0, 0);
            z = __builtin_amdgcn_mfma_f32_16x16x32_bf16(qfrag[it][1], bfrag[ft][1], z, 0, 0, 0);
#pragma unroll
            for (int r = 0; r < 4; ++r) {
                float e = __builtin_amdgcn_exp2f(z[r]);
                qp[ft][r] = e;
                denom[r] += e * ksr[ft];
            }
        }
#pragma unroll
        for (int r = 0; r < 4; ++r) {
            denom[r] += __shfl_xor(denom[r], 1);
            denom[r] += __shfl_xor(denom[r], 2);
            denom[r] += __shfl_xor(denom[r], 4);
            denom[r] += __shfl_xor(denom[r], 8);
            denom[r] = 1.0f / denom[r];
        }
#pragma unroll
        for (int r = 0; r < 4; ++r) {
            floatx4 o;
#pragma unroll
            for (int ft = 0; ft < 4; ++ft)
                o[ft] = qp[ft][r] * ctxr[ft] * denom[r];
            *(floatx4*)(out + (hbase + row0 + g * 4 + r) * DDIM + fp * 4) = o;
        }
    }
}

extern "C" void kernel_launch(void* const* d_in, const int* in_sizes, int n_in,
                              void* d_out, int out_size, void* d_ws, size_t ws_size,
                              hipStream_t stream) {
    const float* q    = (const float*)d_in[0];
    const float* k    = (const float*)d_in[1];
    const float* v    = (const float*)d_in[2];
    const float* proj = (const float*)d_in[3];
    float* out = (float*)d_out;
    float* ws  = (float*)d_ws;   // 1024 * 128 floats = 512 KB partials

    fa_pass1<<<NHEADS * 32, 256, 0, stream>>>(k, v, proj, ws);
    fa_pass2<<<NHEADS * 32, 256, 0, stream>>>(q, proj, ws, out);
}